// Round 9
// baseline (483.656 us; speedup 1.0000x reference)
//
#include <hip/hip_runtime.h>

#define AANG 180
#define NN 256
#define BCH 12

#ifndef M_PI
#define M_PI 3.14159265358979323846
#endif

__device__ __forceinline__ int iclamp(int v, int lo, int hi) {
    return v < lo ? lo : (v > hi ? hi : v);
}

// ---------------- Radon v10: v9 + wave-uniform sub-tile skipping.
// Per-sample FP arithmetic and accumulation order bit-identical to v9.
// Window math identical to round-5's (correctness-proven), applied at
// 16-iteration sub-tile granularity so static unrolling survives.
#define LSTR 259
#define LROWSMAX 130

__global__ __launch_bounds__(1024, 1)
void radon_kernel(const float* __restrict__ x, float* __restrict__ partial) {
    __shared__ float tile[LROWSMAX * LSTR];  // 134,680 B
    __shared__ float red[2][1024];           // + 8 KB
    int blk = blockIdx.x;        // ((n*2)+h)*30 + g
    int g = blk % 30;
    int t = blk / 30;
    int h = t & 1;
    int n = t >> 1;
    int tid = threadIdx.x;
    int lx = tid & 255;
    int qid = tid >> 8;
    int R0 = h ? 127 : -1;
    int nrows = h ? 130 : 129;
    unsigned lrmax = h ? 128u : 127u;
    float Ylo = h ? 127.0f : -1.0f;
    float Yhi1 = h ? 256.0f : 127.0f;  // Yhi + 1
    const float* img = x + (size_t)n * NN * NN;

    for (int rr = qid; rr < nrows; rr += 4) {
        int gr = R0 + rr;
        bool rok = (gr >= 0) && (gr < NN);
        const float* row = img + gr * NN;
        int gc = lx - 1;
        tile[rr * LSTR + lx] = (rok && gc >= 0) ? row[gc] : 0.0f;
        if (lx < 3) {
            int gc2 = 255 + lx;
            tile[rr * LSTR + 256 + lx] = (rok && gc2 < NN) ? row[gc2] : 0.0f;
        }
    }
    __syncthreads();

    float fx = (float)lx;
    int ubase = qid * 64;
    int wave = tid >> 6;
    float fxA = (float)((wave & 3) * 64);  // wave's x extremes
    float fxB = fxA + 63.0f;

    for (int pp = 0; pp < 3; ++pp) {
        int a0 = g + (2 * pp) * 30;
        int a1 = a0 + 30;
        float th0 = (float)((double)a0 * (M_PI / 180.0));
        float th1 = (float)((double)a1 * (M_PI / 180.0));
        float c0 = cosf(th0), s0 = sinf(th0);
        float c1 = cosf(th1), s1 = sinf(th1);
        float kx0 = -128.0f * (c0 + s0 - 1.0f), ky0 = -128.0f * (c0 - s0 - 1.0f);
        float kx1 = -128.0f * (c1 + s1 - 1.0f), ky1 = -128.0f * (c1 - s1 - 1.0f);
        float xcon0 = c0 * fx + kx0;   // sx = fma(s0, fy, xcon0)
        float dcon0 = -s0 * fx + ky0;  // sy = fma(c0, fy, dcon0)
        float xcon1 = c1 * fx + kx1;
        float dcon1 = -s1 * fx + ky1;

        // conservative valid-u window per angle (round-5 math), then union
        float lo0, hi0, lo1, hi1;
        {
            float loY, hiY;
            if (__builtin_fabsf(c0) > 1e-5f) {
                float dA = -s0 * fxA + ky0, dB = -s0 * fxB + ky0;
                float t1 = (Ylo - dA) / c0, t2 = (Yhi1 - dA) / c0;
                float t3 = (Ylo - dB) / c0, t4 = (Yhi1 - dB) / c0;
                loY = fminf(fminf(t1, t2), fminf(t3, t4));
                hiY = fmaxf(fmaxf(t1, t2), fmaxf(t3, t4));
            } else { loY = 0.0f; hiY = 256.0f; }
            float loX, hiX;
            if (s0 > 1e-5f) {
                float xA = c0 * fxA + kx0, xB = c0 * fxB + kx0;
                float t1 = (-1.0f - xA) / s0, t2 = (257.0f - xA) / s0;
                float t3 = (-1.0f - xB) / s0, t4 = (257.0f - xB) / s0;
                loX = fminf(fminf(t1, t2), fminf(t3, t4));
                hiX = fmaxf(fmaxf(t1, t2), fmaxf(t3, t4));
            } else { loX = 0.0f; hiX = 256.0f; }
            lo0 = fmaxf(fmaxf(loY, loX) - 2.0f, 0.0f);
            hi0 = fminf(fminf(hiY, hiX) + 3.0f, 256.0f);
        }
        {
            float loY, hiY;
            if (__builtin_fabsf(c1) > 1e-5f) {
                float dA = -s1 * fxA + ky1, dB = -s1 * fxB + ky1;
                float t1 = (Ylo - dA) / c1, t2 = (Yhi1 - dA) / c1;
                float t3 = (Ylo - dB) / c1, t4 = (Yhi1 - dB) / c1;
                loY = fminf(fminf(t1, t2), fminf(t3, t4));
                hiY = fmaxf(fmaxf(t1, t2), fmaxf(t3, t4));
            } else { loY = 0.0f; hiY = 256.0f; }
            float loX, hiX;
            if (s1 > 1e-5f) {
                float xA = c1 * fxA + kx1, xB = c1 * fxB + kx1;
                float t1 = (-1.0f - xA) / s1, t2 = (257.0f - xA) / s1;
                float t3 = (-1.0f - xB) / s1, t4 = (257.0f - xB) / s1;
                loX = fminf(fminf(t1, t2), fminf(t3, t4));
                hiX = fmaxf(fmaxf(t1, t2), fmaxf(t3, t4));
            } else { loX = 0.0f; hiX = 256.0f; }
            lo1 = fmaxf(fmaxf(loY, loX) - 2.0f, 0.0f);
            hi1 = fminf(fminf(hiY, hiX) + 3.0f, 256.0f);
        }
        int umin = (int)fminf(lo0, lo1);
        int umax = (int)fmaxf(hi0, hi1);
        umin = __builtin_amdgcn_readfirstlane(umin);
        umax = __builtin_amdgcn_readfirstlane(umax);

        float acc0 = 0.0f, acc1 = 0.0f;
#pragma unroll
        for (int st = 0; st < 4; ++st) {
            int t0i = ubase + st * 16;
            if (t0i + 16 <= umin || t0i >= umax) continue;  // wave-uniform skip
#pragma unroll 4
            for (int i = 0; i < 16; ++i) {
                float fy = (float)(t0i + i);
                float sy0 = __builtin_fmaf(c0, fy, dcon0);
                float sx0 = __builtin_fmaf(s0, fy, xcon0);
                float sy1 = __builtin_fmaf(c1, fy, dcon1);
                float sx1 = __builtin_fmaf(s1, fy, xcon1);
                float iyf0 = floorf(sy0), ixf0 = floorf(sx0);
                float iyf1 = floorf(sy1), ixf1 = floorf(sx1);
                int lr0 = (int)iyf0 - R0, lc0 = (int)ixf0 + 1;
                int lr1 = (int)iyf1 - R0, lc1 = (int)ixf1 + 1;
                if ((unsigned)lr0 <= lrmax && (unsigned)lc0 <= 256u) {
                    float wy = sy0 - iyf0, wx = sx0 - ixf0;
                    const float* t0p = &tile[lr0 * LSTR + lc0];
                    float v00 = t0p[0], v01 = t0p[1];
                    float v10 = t0p[LSTR], v11 = t0p[LSTR + 1];
                    float wx1 = 1.0f - wx, wy1 = 1.0f - wy;
                    acc0 += wy1 * (wx1 * v00 + wx * v01) + wy * (wx1 * v10 + wx * v11);
                }
                if ((unsigned)lr1 <= lrmax && (unsigned)lc1 <= 256u) {
                    float wy = sy1 - iyf1, wx = sx1 - ixf1;
                    const float* t1p = &tile[lr1 * LSTR + lc1];
                    float v00 = t1p[0], v01 = t1p[1];
                    float v10 = t1p[LSTR], v11 = t1p[LSTR + 1];
                    float wx1 = 1.0f - wx, wy1 = 1.0f - wy;
                    acc1 += wy1 * (wx1 * v00 + wx * v01) + wy * (wx1 * v10 + wx * v11);
                }
            }
        }
        if (pp) __syncthreads();
        red[0][tid] = acc0;
        red[1][tid] = acc1;
        __syncthreads();
        if (tid < 256) {
            float r0 = red[0][tid] + red[0][tid + 256] + red[0][tid + 512] + red[0][tid + 768];
            float r1 = red[1][tid] + red[1][tid + 256] + red[1][tid + 512] + red[1][tid + 768];
            size_t base = (((size_t)h * BCH + n) * AANG);
            partial[(base + a0) * NN + tid] = r0;
            partial[(base + a1) * NN + tid] = r1;
        }
    }
}

// ---------------- W transpose (tiny). ----
__global__ void wtrans_kernel(const float* __restrict__ Wq, const float* __restrict__ Wk,
                              const float* __restrict__ Wv, float* __restrict__ WqT,
                              float* __restrict__ WkT, float* __restrict__ WvT) {
    int idx = blockIdx.x * 256 + threadIdx.x;
    if (idx < AANG * AANG) {
        int p = idx / AANG;
        int j = idx - p * AANG;
        int src = j * AANG + p;
        WqT[idx] = Wq[src];
        WkT[idx] = Wk[src];
        WvT[idx] = Wv[src];
    }
}

// ---------------- QKV: srow transposed [p][8] -> b128 broadcast reads. ----
__global__ void qkv_kernel(const float* __restrict__ partial,
                           const float* __restrict__ WqT, const float* __restrict__ bq,
                           const float* __restrict__ WkT, const float* __restrict__ bk,
                           const float* __restrict__ WvT, const float* __restrict__ bv,
                           float* __restrict__ Q, float* __restrict__ Kt,
                           float* __restrict__ V) {
    __shared__ float srow_t[AANG][8];
    int blk = blockIdx.x;  // n*32 + i8
    int n = blk >> 5;
    int i0 = (blk & 31) * 8;
    int tid = threadIdx.x;  // 256
    const size_t HOFF = (size_t)BCH * AANG * NN;
    if (tid < AANG) {
        size_t idx = (((size_t)n) * AANG + tid) * NN + i0;
        float4 p0 = *(const float4*)&partial[idx];
        float4 p1 = *(const float4*)&partial[idx + 4];
        float4 q0 = *(const float4*)&partial[idx + HOFF];
        float4 q1 = *(const float4*)&partial[idx + HOFF + 4];
        srow_t[tid][0] = p0.x + q0.x;
        srow_t[tid][1] = p0.y + q0.y;
        srow_t[tid][2] = p0.z + q0.z;
        srow_t[tid][3] = p0.w + q0.w;
        srow_t[tid][4] = p1.x + q1.x;
        srow_t[tid][5] = p1.y + q1.y;
        srow_t[tid][6] = p1.z + q1.z;
        srow_t[tid][7] = p1.w + q1.w;
    }
    __syncthreads();
    if (tid < AANG) {
        int j = tid;
        float aq[8], ak[8], av[8];
        float bqv = bq[j], bkv = bk[j], bvv = bv[j];
        for (int r = 0; r < 8; ++r) { aq[r] = bqv; ak[r] = bkv; av[r] = bvv; }
#pragma unroll 2
        for (int p = 0; p < AANG; ++p) {
            float wq = WqT[p * AANG + j];
            float wk = WkT[p * AANG + j];
            float wv = WvT[p * AANG + j];
            float4 sv0 = *(const float4*)&srow_t[p][0];
            float4 sv1 = *(const float4*)&srow_t[p][4];
            aq[0] += sv0.x * wq; ak[0] += sv0.x * wk; av[0] += sv0.x * wv;
            aq[1] += sv0.y * wq; ak[1] += sv0.y * wk; av[1] += sv0.y * wv;
            aq[2] += sv0.z * wq; ak[2] += sv0.z * wk; av[2] += sv0.z * wv;
            aq[3] += sv0.w * wq; ak[3] += sv0.w * wk; av[3] += sv0.w * wv;
            aq[4] += sv1.x * wq; ak[4] += sv1.x * wk; av[4] += sv1.x * wv;
            aq[5] += sv1.y * wq; ak[5] += sv1.y * wk; av[5] += sv1.y * wv;
            aq[6] += sv1.z * wq; ak[6] += sv1.z * wk; av[6] += sv1.z * wv;
            aq[7] += sv1.w * wq; ak[7] += sv1.w * wk; av[7] += sv1.w * wv;
        }
        for (int r = 0; r < 8; ++r) {
            size_t qb = ((size_t)(n * NN + i0 + r)) * AANG + j;
            Q[qb] = aq[r];
            V[qb] = av[r];
        }
        size_t kb = ((size_t)(n * AANG + j)) * NN + i0;
        for (int r = 0; r < 8; ++r) Kt[kb + r] = ak[r];
    }
}

// ---------------- Attention: 4 query rows/block, shfl reductions. ----
__global__ void attn_kernel(const float* __restrict__ Q, const float* __restrict__ Kt,
                            const float* __restrict__ V, float* __restrict__ att_t) {
    __shared__ float qrow[4][AANG];
    __shared__ float prob[4][NN];
    __shared__ float wm[4][4], wsm[4][4];
    int blk = blockIdx.x;  // n*64 + i4
    int n = blk >> 6;
    int i0 = (blk & 63) * 4;
    int tid = threadIdx.x;  // 256: key index
    int wid = tid >> 6;
    if (tid < AANG) {
#pragma unroll
        for (int r = 0; r < 4; ++r)
            qrow[r][tid] = Q[((size_t)(n * NN + i0 + r)) * AANG + tid];
    }
    __syncthreads();
    float d0 = 0.0f, d1 = 0.0f, d2 = 0.0f, d3 = 0.0f;
    const float* kb = Kt + (size_t)n * AANG * NN + tid;
#pragma unroll 4
    for (int j = 0; j < AANG; ++j) {
        float kv = kb[(size_t)j * NN];
        d0 += qrow[0][j] * kv;
        d1 += qrow[1][j] * kv;
        d2 += qrow[2][j] * kv;
        d3 += qrow[3][j] * kv;
    }
    const float rs = 0.0745355992f;  // 1/sqrt(180)
    float l0 = d0 * rs, l1 = d1 * rs, l2 = d2 * rs, l3 = d3 * rs;
    float m0 = l0, m1 = l1, m2 = l2, m3 = l3;
    for (int off = 32; off > 0; off >>= 1) {
        m0 = fmaxf(m0, __shfl_xor(m0, off));
        m1 = fmaxf(m1, __shfl_xor(m1, off));
        m2 = fmaxf(m2, __shfl_xor(m2, off));
        m3 = fmaxf(m3, __shfl_xor(m3, off));
    }
    if ((tid & 63) == 0) { wm[0][wid] = m0; wm[1][wid] = m1; wm[2][wid] = m2; wm[3][wid] = m3; }
    __syncthreads();
    float mx0 = fmaxf(fmaxf(wm[0][0], wm[0][1]), fmaxf(wm[0][2], wm[0][3]));
    float mx1 = fmaxf(fmaxf(wm[1][0], wm[1][1]), fmaxf(wm[1][2], wm[1][3]));
    float mx2 = fmaxf(fmaxf(wm[2][0], wm[2][1]), fmaxf(wm[2][2], wm[2][3]));
    float mx3 = fmaxf(fmaxf(wm[3][0], wm[3][1]), fmaxf(wm[3][2], wm[3][3]));
    float e0 = expf(l0 - mx0), e1 = expf(l1 - mx1);
    float e2 = expf(l2 - mx2), e3 = expf(l3 - mx3);
    float s0 = e0, s1 = e1, s2 = e2, s3 = e3;
    for (int off = 32; off > 0; off >>= 1) {
        s0 += __shfl_xor(s0, off);
        s1 += __shfl_xor(s1, off);
        s2 += __shfl_xor(s2, off);
        s3 += __shfl_xor(s3, off);
    }
    if ((tid & 63) == 0) { wsm[0][wid] = s0; wsm[1][wid] = s1; wsm[2][wid] = s2; wsm[3][wid] = s3; }
    __syncthreads();
    float dn0 = wsm[0][0] + wsm[0][1] + wsm[0][2] + wsm[0][3];
    float dn1 = wsm[1][0] + wsm[1][1] + wsm[1][2] + wsm[1][3];
    float dn2 = wsm[2][0] + wsm[2][1] + wsm[2][2] + wsm[2][3];
    float dn3 = wsm[3][0] + wsm[3][1] + wsm[3][2] + wsm[3][3];
    prob[0][tid] = e0 / dn0;
    prob[1][tid] = e1 / dn1;
    prob[2][tid] = e2 / dn2;
    prob[3][tid] = e3 / dn3;
    __syncthreads();
    if (tid < AANG) {
        float a0 = 0.0f, a1 = 0.0f, a2 = 0.0f, a3 = 0.0f;
        const float* vb = V + (size_t)n * NN * AANG + tid;
#pragma unroll 4
        for (int k = 0; k < NN; ++k) {
            float v = vb[(size_t)k * AANG];
            a0 += prob[0][k] * v;
            a1 += prob[1][k] * v;
            a2 += prob[2][k] * v;
            a3 += prob[3][k] * v;
        }
        float4 st = make_float4(a0, a1, a2, a3);
        *(float4*)&att_t[((size_t)(n * AANG + tid)) * NN + i0] = st;
    }
}

// ---------------- Ramp filter v2: zero-padded scol[512] -> ds_read2 pairs,
// no boundary selects. Bitwise-identical contributions & order. ----
__global__ void filter_kernel(const float* __restrict__ att_t, float* __restrict__ filt) {
    __shared__ float scol[512];  // [128..383] = data, rest 0
    __shared__ float coef[128];
    int blk = blockIdx.x;  // n*AANG + a
    int tid = threadIdx.x;
    const float* src = &att_t[(size_t)blk * NN];
    scol[tid] = (tid >= 128) ? src[tid - 128] : 0.0f;
    scol[tid + 256] = (tid < 128) ? src[tid + 128] : 0.0f;
    if (tid < 128) {
        float d = (float)(2 * tid + 1);
        coef[tid] = -2.0f / ((float)(M_PI * M_PI) * d * d);
    }
    __syncthreads();
    const float* c = &scol[tid + 128];
    float acc = 0.5f * c[0];
#pragma unroll 4
    for (int m = 0; m < 128; ++m) {
        int d = 2 * m + 1;
        acc += coef[m] * (c[-d] + c[d]);
    }
    filt[(size_t)blk * NN + tid] = acc;
}

// ---------------- Backprojection v4: edge-padded cols[36][384] -> one
// ds_read2 per sample, no clamps. Values & order bit-identical to v3. ----
#define ACH 36
#define BPW 384
__global__ __launch_bounds__(1024)
void backproj_kernel(const float* __restrict__ filt, float* __restrict__ out) {
    __shared__ float cols[ACH][BPW];  // 55.3 KB
    __shared__ float cs[AANG], sn[AANG];
    int blk = blockIdx.x;  // n*64 + rg
    int n = blk >> 6;
    int rg = blk & 63;
    int tid = threadIdx.x;
    int col = tid & 255;
    int rslot = tid >> 8;
    int r = rg * 4 + rslot;
    if (tid < AANG) {
        float th = (float)((double)tid * (M_PI / 180.0));
        cs[tid] = cosf(th);
        sn[tid] = sinf(th);
    }
    float xr = (float)(r - 128);
    float yr = (float)(col - 128);
    float acc = 0.0f;
    const float* fb = filt + (size_t)n * AANG * NN;
    for (int ch = 0; ch < AANG / ACH; ++ch) {
        __syncthreads();
        for (int idx = tid; idx < ACH * BPW; idx += 1024) {
            int q = idx / BPW;
            int cc = idx - q * BPW;
            int srci = iclamp(cc - 64, 0, NN - 1);
            cols[q][cc] = fb[(size_t)(ch * ACH + q) * NN + srci];
        }
        __syncthreads();
#pragma unroll 4
        for (int q = 0; q < ACH; ++q) {
            int aa = ch * ACH + q;
            float t = yr * cs[aa] - xr * sn[aa] + 128.0f;
            float i0f = floorf(t);
            int i0 = (int)i0f;
            float frac = t - i0f;
            const float* p = &cols[q][i0 + 64];
            float v0 = p[0], v1 = p[1];
            float val = (1.0f - frac) * v0 + frac * v1;
            if (t >= 0.0f && t <= 255.0f) acc += val;
        }
    }
    bool inside = (xr * xr + yr * yr) <= 16384.0f;
    out[((size_t)(n * NN + r)) * NN + col] = inside ? acc * (float)(M_PI / 360.0) : 0.0f;
}

extern "C" void kernel_launch(void* const* d_in, const int* in_sizes, int n_in,
                              void* d_out, int out_size, void* d_ws, size_t ws_size,
                              hipStream_t stream) {
    const float* x  = (const float*)d_in[0];
    const float* Wq = (const float*)d_in[1];
    const float* bq = (const float*)d_in[2];
    const float* Wk = (const float*)d_in[3];
    const float* bk = (const float*)d_in[4];
    const float* Wv = (const float*)d_in[5];
    const float* bv = (const float*)d_in[6];
    float* out = (float*)d_out;
    float* ws = (float*)d_ws;

    const size_t SZ = (size_t)BCH * NN * AANG;
    float* P     = ws;           // partial[2][n][a][x]
    float* Q     = P + 2 * SZ;
    float* Kt    = Q + SZ;
    float* V     = Kt + SZ;
    float* att_t = V + SZ;
    float* WqT   = att_t;        // alias: dead before attn writes att_t
    float* WkT   = WqT + AANG * AANG;
    float* WvT   = WkT + AANG * AANG;
    float* filt  = P;            // alias: partials dead after qkv

    wtrans_kernel<<<(AANG * AANG + 255) / 256, 256, 0, stream>>>(Wq, Wk, Wv, WqT, WkT, WvT);
    radon_kernel<<<BCH * 2 * 30, 1024, 0, stream>>>(x, P);
    qkv_kernel<<<BCH * (NN / 8), 256, 0, stream>>>(P, WqT, bq, WkT, bk, WvT, bv, Q, Kt, V);
    attn_kernel<<<BCH * (NN / 4), NN, 0, stream>>>(Q, Kt, V, att_t);
    filter_kernel<<<BCH * AANG, NN, 0, stream>>>(att_t, filt);
    backproj_kernel<<<BCH * (NN / 4), 1024, 0, stream>>>(filt, out);
}

// Round 10
// 448.566 us; speedup vs baseline: 1.0782x; 1.0782x over previous
//
#include <hip/hip_runtime.h>

#define AANG 180
#define NN 256
#define BCH 12

#ifndef M_PI
#define M_PI 3.14159265358979323846
#endif

__device__ __forceinline__ int iclamp(int v, int lo, int hi) {
    return v < lo ? lo : (v > hi ? hi : v);
}

// ---------------- Radon v9 (R8-exact, proven 242 us): half-image LDS residency,
// dual-angle ILP, unroll-4, unsigned-range predicates. Do NOT touch the
// per-sample FP expressions (floor discontinuities -> softmax flips).
#define LSTR 259
#define LROWSMAX 130

__global__ __launch_bounds__(1024, 1)
void radon_kernel(const float* __restrict__ x, float* __restrict__ partial) {
    __shared__ float tile[LROWSMAX * LSTR];  // 134,680 B
    __shared__ float red[2][1024];           // + 8 KB
    int blk = blockIdx.x;        // ((n*2)+h)*30 + g
    int g = blk % 30;
    int t = blk / 30;
    int h = t & 1;
    int n = t >> 1;
    int tid = threadIdx.x;
    int lx = tid & 255;
    int qid = tid >> 8;
    int R0 = h ? 127 : -1;
    int nrows = h ? 130 : 129;
    unsigned lrmax = h ? 128u : 127u;  // valid lr in [0, lrmax]
    const float* img = x + (size_t)n * NN * NN;

    for (int rr = qid; rr < nrows; rr += 4) {
        int gr = R0 + rr;
        bool rok = (gr >= 0) && (gr < NN);
        const float* row = img + gr * NN;
        int gc = lx - 1;
        tile[rr * LSTR + lx] = (rok && gc >= 0) ? row[gc] : 0.0f;
        if (lx < 3) {
            int gc2 = 255 + lx;
            tile[rr * LSTR + 256 + lx] = (rok && gc2 < NN) ? row[gc2] : 0.0f;
        }
    }
    __syncthreads();

    float fx = (float)lx;
    int ubase = qid * 64;

    for (int pp = 0; pp < 3; ++pp) {
        int a0 = g + (2 * pp) * 30;
        int a1 = a0 + 30;
        float th0 = (float)((double)a0 * (M_PI / 180.0));
        float th1 = (float)((double)a1 * (M_PI / 180.0));
        float c0 = cosf(th0), s0 = sinf(th0);
        float c1 = cosf(th1), s1 = sinf(th1);
        float kx0 = -128.0f * (c0 + s0 - 1.0f), ky0 = -128.0f * (c0 - s0 - 1.0f);
        float kx1 = -128.0f * (c1 + s1 - 1.0f), ky1 = -128.0f * (c1 - s1 - 1.0f);
        float xcon0 = c0 * fx + kx0;   // sx = fma(s0, fy, xcon0)
        float dcon0 = -s0 * fx + ky0;  // sy = fma(c0, fy, dcon0)
        float xcon1 = c1 * fx + kx1;
        float dcon1 = -s1 * fx + ky1;
        float acc0 = 0.0f, acc1 = 0.0f;
#pragma unroll 4
        for (int i = 0; i < 64; ++i) {
            float fy = (float)(ubase + i);
            float sy0 = __builtin_fmaf(c0, fy, dcon0);
            float sx0 = __builtin_fmaf(s0, fy, xcon0);
            float sy1 = __builtin_fmaf(c1, fy, dcon1);
            float sx1 = __builtin_fmaf(s1, fy, xcon1);
            float iyf0 = floorf(sy0), ixf0 = floorf(sx0);
            float iyf1 = floorf(sy1), ixf1 = floorf(sx1);
            int lr0 = (int)iyf0 - R0, lc0 = (int)ixf0 + 1;
            int lr1 = (int)iyf1 - R0, lc1 = (int)ixf1 + 1;
            if ((unsigned)lr0 <= lrmax && (unsigned)lc0 <= 256u) {
                float wy = sy0 - iyf0, wx = sx0 - ixf0;
                const float* t0 = &tile[lr0 * LSTR + lc0];
                float v00 = t0[0], v01 = t0[1];
                float v10 = t0[LSTR], v11 = t0[LSTR + 1];
                float wx1 = 1.0f - wx, wy1 = 1.0f - wy;
                acc0 += wy1 * (wx1 * v00 + wx * v01) + wy * (wx1 * v10 + wx * v11);
            }
            if ((unsigned)lr1 <= lrmax && (unsigned)lc1 <= 256u) {
                float wy = sy1 - iyf1, wx = sx1 - ixf1;
                const float* t1 = &tile[lr1 * LSTR + lc1];
                float v00 = t1[0], v01 = t1[1];
                float v10 = t1[LSTR], v11 = t1[LSTR + 1];
                float wx1 = 1.0f - wx, wy1 = 1.0f - wy;
                acc1 += wy1 * (wx1 * v00 + wx * v01) + wy * (wx1 * v10 + wx * v11);
            }
        }
        if (pp) __syncthreads();
        red[0][tid] = acc0;
        red[1][tid] = acc1;
        __syncthreads();
        if (tid < 256) {
            float r0 = red[0][tid] + red[0][tid + 256] + red[0][tid + 512] + red[0][tid + 768];
            float r1 = red[1][tid] + red[1][tid + 256] + red[1][tid + 512] + red[1][tid + 768];
            size_t base = (((size_t)h * BCH + n) * AANG);
            partial[(base + a0) * NN + tid] = r0;
            partial[(base + a1) * NN + tid] = r1;
        }
    }
}

// ---------------- W transpose (tiny). ----
__global__ void wtrans_kernel(const float* __restrict__ Wq, const float* __restrict__ Wk,
                              const float* __restrict__ Wv, float* __restrict__ WqT,
                              float* __restrict__ WkT, float* __restrict__ WvT) {
    int idx = blockIdx.x * 256 + threadIdx.x;
    if (idx < AANG * AANG) {
        int p = idx / AANG;
        int j = idx - p * AANG;
        int src = j * AANG + p;
        WqT[idx] = Wq[src];
        WkT[idx] = Wk[src];
        WvT[idx] = Wv[src];
    }
}

// ---------------- QKV v4: Q,K row-major (coalesced stores), V transposed (Vt).
__global__ void qkv_kernel(const float* __restrict__ partial,
                           const float* __restrict__ WqT, const float* __restrict__ bq,
                           const float* __restrict__ WkT, const float* __restrict__ bk,
                           const float* __restrict__ WvT, const float* __restrict__ bv,
                           float* __restrict__ Q, float* __restrict__ K,
                           float* __restrict__ Vt) {
    __shared__ float srow_t[AANG][8];
    int blk = blockIdx.x;  // n*32 + i8
    int n = blk >> 5;
    int i0 = (blk & 31) * 8;
    int tid = threadIdx.x;  // 256
    const size_t HOFF = (size_t)BCH * AANG * NN;
    if (tid < AANG) {
        size_t idx = (((size_t)n) * AANG + tid) * NN + i0;
        float4 p0 = *(const float4*)&partial[idx];
        float4 p1 = *(const float4*)&partial[idx + 4];
        float4 q0 = *(const float4*)&partial[idx + HOFF];
        float4 q1 = *(const float4*)&partial[idx + HOFF + 4];
        srow_t[tid][0] = p0.x + q0.x;
        srow_t[tid][1] = p0.y + q0.y;
        srow_t[tid][2] = p0.z + q0.z;
        srow_t[tid][3] = p0.w + q0.w;
        srow_t[tid][4] = p1.x + q1.x;
        srow_t[tid][5] = p1.y + q1.y;
        srow_t[tid][6] = p1.z + q1.z;
        srow_t[tid][7] = p1.w + q1.w;
    }
    __syncthreads();
    if (tid < AANG) {
        int j = tid;
        float aq[8], ak[8], av[8];
        float bqv = bq[j], bkv = bk[j], bvv = bv[j];
        for (int r = 0; r < 8; ++r) { aq[r] = bqv; ak[r] = bkv; av[r] = bvv; }
#pragma unroll 4
        for (int p = 0; p < AANG; ++p) {
            float wq = WqT[p * AANG + j];
            float wk = WkT[p * AANG + j];
            float wv = WvT[p * AANG + j];
            float4 sv0 = *(const float4*)&srow_t[p][0];
            float4 sv1 = *(const float4*)&srow_t[p][4];
            aq[0] += sv0.x * wq; ak[0] += sv0.x * wk; av[0] += sv0.x * wv;
            aq[1] += sv0.y * wq; ak[1] += sv0.y * wk; av[1] += sv0.y * wv;
            aq[2] += sv0.z * wq; ak[2] += sv0.z * wk; av[2] += sv0.z * wv;
            aq[3] += sv0.w * wq; ak[3] += sv0.w * wk; av[3] += sv0.w * wv;
            aq[4] += sv1.x * wq; ak[4] += sv1.x * wk; av[4] += sv1.x * wv;
            aq[5] += sv1.y * wq; ak[5] += sv1.y * wk; av[5] += sv1.y * wv;
            aq[6] += sv1.z * wq; ak[6] += sv1.z * wk; av[6] += sv1.z * wv;
            aq[7] += sv1.w * wq; ak[7] += sv1.w * wk; av[7] += sv1.w * wv;
        }
        for (int r = 0; r < 8; ++r) {
            size_t qb = ((size_t)(n * NN + i0 + r)) * AANG + j;
            Q[qb] = aq[r];  // coalesced over j
            K[qb] = ak[r];  // row-major, coalesced over j
        }
        size_t vb = ((size_t)(n * AANG + j)) * NN + i0;
        float4 v0 = make_float4(av[0], av[1], av[2], av[3]);
        float4 v1 = make_float4(av[4], av[5], av[6], av[7]);
        *(float4*)&Vt[vb] = v0;
        *(float4*)&Vt[vb + 4] = v1;
    }
}

// ---------------- Attention v4: 8 query rows/block; K row-major float4 streams,
// Vt float4 streams; b128 LDS broadcasts. Per-accumulator order (j,k ascending)
// identical to previous passing versions. ----
__global__ void attn_kernel(const float* __restrict__ Q, const float* __restrict__ K,
                            const float* __restrict__ Vt, float* __restrict__ att_t) {
    __shared__ float qrow[8][AANG];   // 180*4 = 720 B row stride (16B-aligned)
    __shared__ float prob[8][NN];
    __shared__ float wm[8][4], wsm[8][4];
    int blk = blockIdx.x;  // n*32 + i8
    int n = blk >> 5;
    int i0 = (blk & 31) * 8;
    int tid = threadIdx.x;  // 256: key index k
    int wid = tid >> 6;
    if (tid < AANG) {
#pragma unroll
        for (int r = 0; r < 8; ++r)
            qrow[r][tid] = Q[((size_t)(n * NN + i0 + r)) * AANG + tid];
    }
    __syncthreads();
    float d[8];
#pragma unroll
    for (int r = 0; r < 8; ++r) d[r] = 0.0f;
    const float* krow = K + ((size_t)(n * NN) + tid) * AANG;  // this key's row
#pragma unroll 3
    for (int jj = 0; jj < AANG / 4; ++jj) {
        float4 kv = *(const float4*)&krow[jj * 4];
#pragma unroll
        for (int r = 0; r < 8; ++r) {
            float4 qv = *(const float4*)&qrow[r][jj * 4];
            d[r] += qv.x * kv.x;
            d[r] += qv.y * kv.y;
            d[r] += qv.z * kv.z;
            d[r] += qv.w * kv.w;
        }
    }
    const float rs = 0.0745355992f;  // 1/sqrt(180)
    float l[8], m[8], e[8], s[8];
#pragma unroll
    for (int r = 0; r < 8; ++r) { l[r] = d[r] * rs; m[r] = l[r]; }
    for (int off = 32; off > 0; off >>= 1) {
#pragma unroll
        for (int r = 0; r < 8; ++r) m[r] = fmaxf(m[r], __shfl_xor(m[r], off));
    }
    if ((tid & 63) == 0) {
#pragma unroll
        for (int r = 0; r < 8; ++r) wm[r][wid] = m[r];
    }
    __syncthreads();
#pragma unroll
    for (int r = 0; r < 8; ++r) {
        float mx = fmaxf(fmaxf(wm[r][0], wm[r][1]), fmaxf(wm[r][2], wm[r][3]));
        e[r] = expf(l[r] - mx);
        s[r] = e[r];
    }
    for (int off = 32; off > 0; off >>= 1) {
#pragma unroll
        for (int r = 0; r < 8; ++r) s[r] += __shfl_xor(s[r], off);
    }
    if ((tid & 63) == 0) {
#pragma unroll
        for (int r = 0; r < 8; ++r) wsm[r][wid] = s[r];
    }
    __syncthreads();
#pragma unroll
    for (int r = 0; r < 8; ++r) {
        float dn = wsm[r][0] + wsm[r][1] + wsm[r][2] + wsm[r][3];
        prob[r][tid] = e[r] / dn;
    }
    __syncthreads();
    if (tid < AANG) {
        float a[8];
#pragma unroll
        for (int r = 0; r < 8; ++r) a[r] = 0.0f;
        const float* vrow = Vt + ((size_t)(n * AANG) + tid) * NN;  // this j's row
#pragma unroll 4
        for (int kk = 0; kk < NN / 4; ++kk) {
            float4 v4 = *(const float4*)&vrow[kk * 4];
#pragma unroll
            for (int r = 0; r < 8; ++r) {
                float4 p4 = *(const float4*)&prob[r][kk * 4];
                a[r] += p4.x * v4.x;
                a[r] += p4.y * v4.y;
                a[r] += p4.z * v4.z;
                a[r] += p4.w * v4.w;
            }
        }
        size_t ob = ((size_t)(n * AANG + tid)) * NN + i0;
        *(float4*)&att_t[ob] = make_float4(a[0], a[1], a[2], a[3]);
        *(float4*)&att_t[ob + 4] = make_float4(a[4], a[5], a[6], a[7]);
    }
}

// ---------------- Ramp filter v2: zero-padded scol, no boundary selects. ----
__global__ void filter_kernel(const float* __restrict__ att_t, float* __restrict__ filt) {
    __shared__ float scol[512];  // [128..383] = data, rest 0
    __shared__ float coef[128];
    int blk = blockIdx.x;  // n*AANG + a
    int tid = threadIdx.x;
    const float* src = &att_t[(size_t)blk * NN];
    scol[tid] = (tid >= 128) ? src[tid - 128] : 0.0f;
    scol[tid + 256] = (tid < 128) ? src[tid + 128] : 0.0f;
    if (tid < 128) {
        float d = (float)(2 * tid + 1);
        coef[tid] = -2.0f / ((float)(M_PI * M_PI) * d * d);
    }
    __syncthreads();
    const float* c = &scol[tid + 128];
    float acc = 0.5f * c[0];
#pragma unroll 4
    for (int m = 0; m < 128; ++m) {
        int d = 2 * m + 1;
        acc += coef[m] * (c[-d] + c[d]);
    }
    filt[(size_t)blk * NN + tid] = acc;
}

// ---------------- Backprojection v3 (R8-exact): block = (n, 4-row group);
// 1024 threads; 36-angle chunks staged cooperatively. ----
#define ACH 36
__global__ __launch_bounds__(1024)
void backproj_kernel(const float* __restrict__ filt, float* __restrict__ out) {
    __shared__ float cols[ACH][NN];
    __shared__ float cs[AANG], sn[AANG];
    int blk = blockIdx.x;  // n*64 + rg
    int n = blk >> 6;
    int rg = blk & 63;
    int tid = threadIdx.x;
    int col = tid & 255;
    int rslot = tid >> 8;
    int r = rg * 4 + rslot;
    if (tid < AANG) {
        float th = (float)((double)tid * (M_PI / 180.0));
        cs[tid] = cosf(th);
        sn[tid] = sinf(th);
    }
    float xr = (float)(r - 128);
    float yr = (float)(col - 128);
    float acc = 0.0f;
    const float* fb = filt + (size_t)n * AANG * NN;
    for (int ch = 0; ch < AANG / ACH; ++ch) {
        __syncthreads();
        for (int idx = tid; idx < ACH * NN; idx += 1024) {
            int q = idx >> 8;
            int cc = idx & 255;
            cols[q][cc] = fb[(size_t)(ch * ACH + q) * NN + cc];
        }
        __syncthreads();
#pragma unroll 4
        for (int q = 0; q < ACH; ++q) {
            int aa = ch * ACH + q;
            float t = yr * cs[aa] - xr * sn[aa] + 128.0f;
            float i0f = floorf(t);
            int i0 = (int)i0f;
            float frac = t - i0f;
            int c0 = iclamp(i0, 0, NN - 1);
            int c1 = iclamp(i0 + 1, 0, NN - 1);
            float val = (1.0f - frac) * cols[q][c0] + frac * cols[q][c1];
            if (t >= 0.0f && t <= 255.0f) acc += val;
        }
    }
    bool inside = (xr * xr + yr * yr) <= 16384.0f;
    out[((size_t)(n * NN + r)) * NN + col] = inside ? acc * (float)(M_PI / 360.0) : 0.0f;
}

extern "C" void kernel_launch(void* const* d_in, const int* in_sizes, int n_in,
                              void* d_out, int out_size, void* d_ws, size_t ws_size,
                              hipStream_t stream) {
    const float* x  = (const float*)d_in[0];
    const float* Wq = (const float*)d_in[1];
    const float* bq = (const float*)d_in[2];
    const float* Wk = (const float*)d_in[3];
    const float* bk = (const float*)d_in[4];
    const float* Wv = (const float*)d_in[5];
    const float* bv = (const float*)d_in[6];
    float* out = (float*)d_out;
    float* ws = (float*)d_ws;

    const size_t SZ = (size_t)BCH * NN * AANG;
    float* P     = ws;           // partial[2][n][a][x]
    float* Q     = P + 2 * SZ;
    float* K     = Q + SZ;       // row-major, same layout as Q
    float* Vt    = K + SZ;       // transposed: Vt[n][j][i]
    float* att_t = Vt + SZ;
    float* WqT   = att_t;        // alias: dead before attn writes att_t
    float* WkT   = WqT + AANG * AANG;
    float* WvT   = WkT + AANG * AANG;
    float* filt  = P;            // alias: partials dead after qkv

    wtrans_kernel<<<(AANG * AANG + 255) / 256, 256, 0, stream>>>(Wq, Wk, Wv, WqT, WkT, WvT);
    radon_kernel<<<BCH * 2 * 30, 1024, 0, stream>>>(x, P);
    qkv_kernel<<<BCH * (NN / 8), 256, 0, stream>>>(P, WqT, bq, WkT, bk, WvT, bv, Q, K, Vt);
    attn_kernel<<<BCH * (NN / 8), 256, 0, stream>>>(Q, K, Vt, att_t);
    filter_kernel<<<BCH * AANG, NN, 0, stream>>>(att_t, filt);
    backproj_kernel<<<BCH * (NN / 4), 1024, 0, stream>>>(filt, out);
}